// Round 4
// baseline (214.112 us; speedup 1.0000x reference)
//
#include <hip/hip_runtime.h>
#include <cstdint>
#include <cstddef>
#include <math.h>

typedef unsigned short u16;

#define S_LEN 2048
#define EMB   1024
#define HID   1024
#define NB    4

using bf16x8 = __attribute__((ext_vector_type(8))) __bf16;
using f32x4  = __attribute__((ext_vector_type(4))) float;

// ---------- helpers ----------

__device__ __forceinline__ u16 f2bf(float f) {
  union { float f; uint32_t u; } c; c.f = f;
  uint32_t u = c.u;
  uint32_t r = (u + 0x7fffu + ((u >> 16) & 1u)) >> 16;  // RNE
  return (u16)r;
}

__device__ __forceinline__ void gld_lds16(const u16* g, u16* l) {
  auto gp = (const __attribute__((address_space(1))) uint32_t*)(uintptr_t)(const void*)g;
  auto lp = (__attribute__((address_space(3))) uint32_t*)(uintptr_t)(void*)l;
  __builtin_amdgcn_global_load_lds(gp, lp, 16, 0, 0);
}

// ---------- fp32 -> bf16 converts ----------

__global__ void cvt_f32_bf16(const float* __restrict__ in, u16* __restrict__ out, int n4) {
  int i = blockIdx.x * blockDim.x + threadIdx.x;
  int stride = gridDim.x * blockDim.x;
  for (; i < n4; i += stride) {
    float4 v = reinterpret_cast<const float4*>(in)[i];
    reinterpret_cast<ushort4*>(out)[i] =
      make_ushort4(f2bf(v.x), f2bf(v.y), f2bf(v.z), f2bf(v.w));
  }
}

__global__ void cvt3_f32_bf16(const float* __restrict__ a, const float* __restrict__ b,
                              const float* __restrict__ c, u16* __restrict__ out, int n4) {
  const float* src = (blockIdx.y == 0) ? a : (blockIdx.y == 1) ? b : c;
  u16* dst = out + (size_t)blockIdx.y * (size_t)n4 * 4;
  int i = blockIdx.x * blockDim.x + threadIdx.x;
  int stride = gridDim.x * blockDim.x;
  for (; i < n4; i += stride) {
    float4 v = reinterpret_cast<const float4*>(src)[i];
    reinterpret_cast<ushort4*>(dst)[i] =
      make_ushort4(f2bf(v.x), f2bf(v.y), f2bf(v.z), f2bf(v.w));
  }
}

// ============================================================================
// gemm256: fused QKV projection, read-ahead pipelined 256x256 tile.
// A = xb [8192][1024], B = wqkv [3072][1024], K=1024, BK=32, NT=32.
// 8 waves (2M x 4N), per-wave out 128x64. LDS: 4 slots x 32KB = 128KB.
// Schedule per tile t (2 phases, 2 barriers):
//   ph1: stage A0,B0 of tile t+3; vmcnt(6) [tile t+1 landed]; barrier;
//        ds_read CUR.a1 (buf t) + NXT.a0,b (buf t+1); MFMA acc[0..3]+=CUR.a0*CUR.b
//   ph2: stage A1,B1 of tile t+3; MFMA acc[4..7]+=CUR.a1*CUR.b; barrier
// Fragment reads are consumed one tile (>=2 phases) after issue -> LDS latency
// hidden under MFMA. vmcnt never drains to 0 in the loop.
// XOR chunk swizzle (involution) applied to global source + ds_read addr.
// ============================================================================

__global__ __launch_bounds__(512, 2)
void gemm_qkv(const u16* __restrict__ A, const u16* __restrict__ B, u16* __restrict__ QK,
              const float* __restrict__ b0, const float* __restrict__ b1,
              const float* __restrict__ b2, u16* __restrict__ VT)
{
  constexpr int K  = 1024;
  constexpr int N  = 3072;
  constexpr int BK = 32;
  constexpr int NT = K / BK;            // 32
  constexpr long M = (long)NB * S_LEN;  // 8192

  __shared__ __align__(16) u16 smem[4 * 16384];   // 128 KB

  const int tid  = threadIdx.x;
  const int lane = tid & 63;
  const int wave = tid >> 6;
  const int wr   = wave >> 2;        // 0..1
  const int wc   = wave & 3;         // 0..3
  const int bm   = blockIdx.y * 256;
  const int bn   = blockIdx.x * 256;

  // staging source addresses (2 row-steps of 128 for A and B)
  const int r0  = tid >> 2;
  const int pch = tid & 3;
  const u16* gA[2]; const u16* gB[2];
#pragma unroll
  for (int s = 0; s < 2; ++s) {
    const int row = s * 128 + r0;
    const int lc  = pch ^ ((row & 3) ^ ((row >> 2) & 3));
    gA[s] = A + (long)(bm + row) * K + lc * 8;
    gB[s] = B + (long)(bn + row) * K + lc * 8;
  }

  // fragment ds_read offsets (u16 units), swizzled
  const int lr  = lane & 15;
  const int kg  = lane >> 4;
  const int sch = kg ^ ((lr & 3) ^ ((lr >> 2) & 3));
  int aofs[8], bofs[4];
#pragma unroll
  for (int m = 0; m < 8; ++m) aofs[m] = (wr * 128 + m * 16 + lr) * 32 + sch * 8;
#pragma unroll
  for (int n = 0; n < 4; ++n) bofs[n] = 8192 + (wc * 64 + n * 16 + lr) * 32 + sch * 8;

  f32x4 acc[8][4] = {};

  // ---- prologue: stage tiles 0,1,2 into slots 0,1,2 ----
#pragma unroll
  for (int p = 0; p < 3; ++p) {
    u16* stg = smem + p * 16384;
    const long ko = (long)p * BK;
    gld_lds16(gA[0] + ko, stg +        wave * 512);
    gld_lds16(gB[0] + ko, stg + 8192 + wave * 512);
    gld_lds16(gA[1] + ko, stg + 4096 +        wave * 512);
    gld_lds16(gB[1] + ko, stg + 4096 + 8192 + wave * 512);
  }
  asm volatile("s_waitcnt vmcnt(8)" ::: "memory");   // tile 0 landed (own wave)
  __builtin_amdgcn_s_barrier();                       // -> all waves' tile 0 landed

  bf16x8 a0e[4], be[4], a1e[4], a0o[4], bo[4], a1o[4];
#pragma unroll
  for (int m = 0; m < 4; ++m) a0e[m] = *reinterpret_cast<const bf16x8*>(smem + aofs[m]);
#pragma unroll
  for (int n = 0; n < 4; ++n) be[n]  = *reinterpret_cast<const bf16x8*>(smem + bofs[n]);

#define TILE_STEP(t, CA0, CB, CA1, NA0, NBv)                                        \
  do {                                                                              \
    const int  _slot = ((t) + 3) & 3;                                               \
    const int  _tp   = ((t) + 3 < NT) ? (t) + 3 : NT - 1;                           \
    const long _ko   = (long)_tp * BK;                                              \
    u16*       _stg  = smem + _slot * 16384;                                        \
    const u16* _cbuf = smem + ((t) & 3) * 16384;                                    \
    const u16* _nbuf = smem + ((((t) + 1 < NT) ? (t) + 1 : NT - 1) & 3) * 16384;    \
    gld_lds16(gA[0] + _ko, _stg +        wave * 512);                               \
    gld_lds16(gB[0] + _ko, _stg + 8192 + wave * 512);                               \
    asm volatile("s_waitcnt vmcnt(6)" ::: "memory");                                \
    __builtin_amdgcn_s_barrier();                                                   \
    _Pragma("unroll")                                                               \
    for (int m = 0; m < 4; ++m)                                                     \
      CA1[m] = *reinterpret_cast<const bf16x8*>(_cbuf + aofs[4 + m]);               \
    _Pragma("unroll")                                                               \
    for (int m = 0; m < 4; ++m)                                                     \
      NA0[m] = *reinterpret_cast<const bf16x8*>(_nbuf + aofs[m]);                   \
    _Pragma("unroll")                                                               \
    for (int n = 0; n < 4; ++n)                                                     \
      NBv[n] = *reinterpret_cast<const bf16x8*>(_nbuf + bofs[n]);                   \
    __builtin_amdgcn_s_setprio(1);                                                  \
    _Pragma("unroll")                                                               \
    for (int m = 0; m < 4; ++m)                                                     \
      _Pragma("unroll")                                                             \
      for (int n = 0; n < 4; ++n)                                                   \
        acc[m][n] = __builtin_amdgcn_mfma_f32_16x16x32_bf16(CA0[m], CB[n],          \
                                                            acc[m][n], 0, 0, 0);    \
    __builtin_amdgcn_s_setprio(0);                                                  \
    gld_lds16(gA[1] + _ko, _stg + 4096 +        wave * 512);                        \
    gld_lds16(gB[1] + _ko, _stg + 4096 + 8192 + wave * 512);                        \
    __builtin_amdgcn_s_setprio(1);                                                  \
    _Pragma("unroll")                                                               \
    for (int m = 0; m < 4; ++m)                                                     \
      _Pragma("unroll")                                                             \
      for (int n = 0; n < 4; ++n)                                                   \
        acc[4 + m][n] = __builtin_amdgcn_mfma_f32_16x16x32_bf16(CA1[m], CB[n],      \
                                                            acc[4 + m][n], 0, 0, 0);\
    __builtin_amdgcn_s_setprio(0);                                                  \
    __builtin_amdgcn_s_barrier();                                                   \
  } while (0)

  for (int t = 0; t < NT; t += 2) {
    TILE_STEP(t,     a0e, be, a1e, a0o, bo);
    TILE_STEP(t + 1, a0o, bo, a1o, a0e, be);
  }
#undef TILE_STEP

  // ---- epilogue: fused QKV routing (C map: col=lane&15, row=(lane>>4)*4+q) ----
  const int sel = bn >> 10;          // 0=Q, 1=K, 2=V (block-uniform)
  const float* bias = (sel == 0) ? b0 : (sel == 1) ? b1 : b2;
#pragma unroll
  for (int n = 0; n < 4; ++n) {
    const int col = bn + wc * 64 + n * 16 + lr;
    const int h   = col & (HID - 1);
    const float bbv = bias[h];
#pragma unroll
    for (int m = 0; m < 8; ++m) {
      const int row0 = bm + wr * 128 + m * 16 + kg * 4;
      if (sel < 2) {
        u16* dst = QK + (long)sel * M * HID + (long)row0 * HID + h;
#pragma unroll
        for (int q = 0; q < 4; ++q)
          dst[(long)q * HID] = f2bf(acc[m][n][q] + bbv);
      } else {
        const int b = row0 >> 11;
        const int s = row0 & (S_LEN - 1);
        ushort4 o = make_ushort4(f2bf(acc[m][n][0] + bbv), f2bf(acc[m][n][1] + bbv),
                                 f2bf(acc[m][n][2] + bbv), f2bf(acc[m][n][3] + bbv));
        *reinterpret_cast<ushort4*>(VT + ((long)b * HID + h) * S_LEN + s) = o;
      }
    }
  }
}

// ============================================================================
// gemm_bt: 128x128 m97-structure GEMM, C[M,N] = A[M,K]*B[N,K]^T  (R2-proven)
// EPI 2: f32 out, *scale, causal mask, triangular grid (scores)
// EPI 3: f32 out, kend = bm+128 (causal PV)
// ============================================================================

#define BM 128
#define BN 128
#define BK 32

template<int EPI>
__global__ __launch_bounds__(256)
void gemm_bt(const u16* __restrict__ A, const u16* __restrict__ B, void* __restrict__ Cv,
             int M, int N, int K, long sA, long sB, long sC, float scale)
{
  const int z = blockIdx.z;
  A += (long)z * sA;
  B += (long)z * sB;

  __shared__ __align__(16) u16 As[BM * BK];
  __shared__ __align__(16) u16 Bs[BN * BK];

  const int t    = threadIdx.x;
  const int lane = t & 63;
  const int wave = t >> 6;
  const int wr   = wave >> 1, wc = wave & 1;

  int bm, bn;
  if constexpr (EPI == 2) {
    const int x = blockIdx.x;
    int bi = (int)((sqrtf(8.0f * (float)x + 1.0f) - 1.0f) * 0.5f);
    while ((bi + 1) * (bi + 2) / 2 <= x) ++bi;
    while (bi * (bi + 1) / 2 > x) --bi;
    bm = bi * BM;
    bn = (x - bi * (bi + 1) / 2) * BN;
  } else {
    bm = (gridDim.y - 1 - blockIdx.y) * BM;   // long blocks first
    bn = blockIdx.x * BN;
  }

  int kend = K;
  if constexpr (EPI == 3) kend = bm + BM;

  f32x4 acc[4][4] = {};

  const int r  = t >> 2, c8 = (t & 3) * 8;
  const u16* gA = A + (long)(bm + r) * K + c8;
  const u16* gB = B + (long)(bn + r) * K + c8;
  u16* sA0 = As + wave * 512;
  u16* sB0 = Bs + wave * 512;

  const int lr = lane & 15;
  const int kg = lane >> 4;
  const int aoff = (wr * 64 + lr) * BK + kg * 8;
  const int boff = (wc * 64 + lr) * BK + kg * 8;

  for (int kt = 0; kt < kend; kt += BK) {
    gld_lds16(gA,                sA0);
    gld_lds16(gA + 64 * (long)K, sA0 + 2048);
    gld_lds16(gB,                sB0);
    gld_lds16(gB + 64 * (long)K, sB0 + 2048);
    gA += BK; gB += BK;
    __syncthreads();

    bf16x8 af[4], bf[4];
#pragma unroll
    for (int i = 0; i < 4; ++i)
      af[i] = *reinterpret_cast<const bf16x8*>(&As[aoff + i * 16 * BK]);
#pragma unroll
    for (int j = 0; j < 4; ++j)
      bf[j] = *reinterpret_cast<const bf16x8*>(&Bs[boff + j * 16 * BK]);
#pragma unroll
    for (int i = 0; i < 4; ++i)
#pragma unroll
      for (int j = 0; j < 4; ++j)
        acc[i][j] = __builtin_amdgcn_mfma_f32_16x16x32_bf16(af[i], bf[j], acc[i][j], 0, 0, 0);
    __syncthreads();
  }

  const int cl = lane & 15;
  const int rg = lane >> 4;

  if constexpr (EPI == 2) {
    float* C = (float*)Cv + (long)z * sC;
#pragma unroll
    for (int j = 0; j < 4; ++j) {
      const int col = bn + wc * 64 + j * 16 + cl;
#pragma unroll
      for (int i = 0; i < 4; ++i) {
        const int row0 = bm + wr * 64 + i * 16 + rg * 4;
#pragma unroll
        for (int q = 0; q < 4; ++q) {
          const int row = row0 + q;
          float v = acc[i][j][q] * scale;
          if (col > row) v = -1e30f;
          C[(long)row * N + col] = v;
        }
      }
    }
  } else {
    float* C = (float*)Cv + (long)z * sC;
#pragma unroll
    for (int j = 0; j < 4; ++j) {
      const int col = bn + wc * 64 + j * 16 + cl;
#pragma unroll
      for (int i = 0; i < 4; ++i) {
        const int row0 = bm + wr * 64 + i * 16 + rg * 4;
#pragma unroll
        for (int q = 0; q < 4; ++q)
          C[(long)(row0 + q) * N + col] = acc[i][j][q];
      }
    }
  }
}

// ---------- causal row softmax: fp32 scores -> bf16 P (kend 128-aligned) ----------

__global__ __launch_bounds__(256)
void softmax_causal(const float* __restrict__ Sc, u16* __restrict__ P, long sS, long sP)
{
  const int row  = blockIdx.x;
  const int z    = blockIdx.y;
  const int kend = ((row >> 7) + 1) << 7;
  const float* srow = Sc + (long)z * sS + (long)row * S_LEN;
  u16*        prow = P  + (long)z * sP + (long)row * S_LEN;
  const int t = threadIdx.x;
  const int lane = t & 63, wave = t >> 6;

  const bool p0 = (4 * t) < kend;
  const bool p1 = (1024 + 4 * t) < kend;

  float4 v0 = make_float4(-1e30f, -1e30f, -1e30f, -1e30f);
  float4 v1 = v0;
  if (p0) v0 = reinterpret_cast<const float4*>(srow)[t];
  if (p1) v1 = reinterpret_cast<const float4*>(srow)[t + 256];

  float mx = fmaxf(fmaxf(fmaxf(v0.x, v0.y), fmaxf(v0.z, v0.w)),
                   fmaxf(fmaxf(v1.x, v1.y), fmaxf(v1.z, v1.w)));

  __shared__ float red[8];
#pragma unroll
  for (int off = 32; off; off >>= 1) mx = fmaxf(mx, __shfl_down(mx, off));
  if (lane == 0) red[wave] = mx;
  __syncthreads();
  mx = fmaxf(fmaxf(red[0], red[1]), fmaxf(red[2], red[3]));

  float e[8];
  e[0] = __expf(v0.x - mx); e[1] = __expf(v0.y - mx);
  e[2] = __expf(v0.z - mx); e[3] = __expf(v0.w - mx);
  e[4] = __expf(v1.x - mx); e[5] = __expf(v1.y - mx);
  e[6] = __expf(v1.z - mx); e[7] = __expf(v1.w - mx);

  float sm = ((e[0] + e[1]) + (e[2] + e[3])) + ((e[4] + e[5]) + (e[6] + e[7]));
#pragma unroll
  for (int off = 32; off; off >>= 1) sm += __shfl_down(sm, off);
  if (lane == 0) red[4 + wave] = sm;
  __syncthreads();
  sm = (red[4] + red[5]) + (red[6] + red[7]);

  const float inv = 1.0f / sm;
  if (p0)
    reinterpret_cast<ushort4*>(prow)[t] =
      make_ushort4(f2bf(e[0]*inv), f2bf(e[1]*inv), f2bf(e[2]*inv), f2bf(e[3]*inv));
  if (p1)
    reinterpret_cast<ushort4*>(prow)[t + 256] =
      make_ushort4(f2bf(e[4]*inv), f2bf(e[5]*inv), f2bf(e[6]*inv), f2bf(e[7]*inv));
}

// ---------- launch ----------

extern "C" void kernel_launch(void* const* d_in, const int* in_sizes, int n_in,
                              void* d_out, int out_size, void* d_ws, size_t ws_size,
                              hipStream_t stream)
{
  const float* x  = (const float*)d_in[0];
  const float* Wq = (const float*)d_in[1];
  const float* bq = (const float*)d_in[2];
  const float* Wk = (const float*)d_in[3];
  const float* bk = (const float*)d_in[4];
  const float* Wv = (const float*)d_in[5];
  const float* bv = (const float*)d_in[6];
  float* out = (float*)d_out;

  const long M = (long)NB * S_LEN;  // 8192

  u16* xb  = (u16*)d_ws;
  u16* wqb = xb  + M * EMB;         // wq/wk/wv contiguous -> fused [3072,1024]
  u16* Qb  = wqb + 3L * HID * EMB;  // Q then K contiguous
  u16* Kb  = Qb  + M * HID;
  u16* VT  = Kb  + M * HID;
  char* rest = (char*)(VT + M * HID);
  const size_t used  = (size_t)(rest - (char*)d_ws);
  const size_t ssz   = (size_t)S_LEN * S_LEN;
  const size_t need4 = used + (size_t)NB * ssz * 4 + (size_t)NB * ssz * 2;
  const int nb = (ws_size >= need4) ? NB : 1;
  float* scores = (float*)rest;
  u16*   P      = (u16*)(rest + (size_t)nb * ssz * 4);

  // fp32 -> bf16
  cvt_f32_bf16<<<2048, 256, 0, stream>>>(x, xb, (int)(M * EMB / 4));
  cvt3_f32_bf16<<<dim3(512, 3), 256, 0, stream>>>(Wq, Wk, Wv, wqb, HID * EMB / 4);

  // fused QKV projection (read-ahead pipelined 256^2)
  gemm_qkv<<<dim3(3 * HID / 256, M / 256), 512, 0, stream>>>(xb, wqb, Qb, bq, bk, bv, VT);

  const float scale = 0.03125f;  // 1/sqrt(1024)
  const int NTb = S_LEN / BM;              // 16 block-rows
  const int TRI = NTb * (NTb + 1) / 2;     // 136 lower-tri blocks

  if (nb == NB) {
    dim3 gs(TRI, 1, NB);
    gemm_bt<2><<<gs, 256, 0, stream>>>(Qb, Kb, scores, S_LEN, S_LEN, HID,
                                       (long)S_LEN * HID, (long)S_LEN * HID, (long)ssz, scale);
    softmax_causal<<<dim3(S_LEN, NB), 256, 0, stream>>>(scores, P, (long)ssz, (long)ssz);
    dim3 gv(HID / BN, S_LEN / BM, NB);
    gemm_bt<3><<<gv, 256, 0, stream>>>(P, VT, out, S_LEN, HID, S_LEN,
                                       (long)ssz, (long)HID * S_LEN, (long)S_LEN * HID, 1.0f);
  } else {
    for (int b = 0; b < NB; ++b) {
      const u16* Qbb = Qb + (long)b * S_LEN * HID;
      const u16* Kbb = Kb + (long)b * S_LEN * HID;
      const u16* VTb = VT + (long)b * HID * S_LEN;
      float* outb = out + (long)b * S_LEN * HID;
      dim3 gs(TRI, 1, 1);
      gemm_bt<2><<<gs, 256, 0, stream>>>(Qbb, Kbb, scores, S_LEN, S_LEN, HID, 0, 0, 0, scale);
      softmax_causal<<<dim3(S_LEN, 1), 256, 0, stream>>>(scores, P, 0, 0);
      dim3 gv(HID / BN, S_LEN / BM, 1);
      gemm_bt<3><<<gv, 256, 0, stream>>>(P, VTb, outb, S_LEN, HID, S_LEN, 0, 0, 0, 1.0f);
    }
  }
}

// Round 5
// 210.170 us; speedup vs baseline: 1.0188x; 1.0188x over previous
//
#include <hip/hip_runtime.h>
#include <cstdint>
#include <cstddef>
#include <math.h>

typedef unsigned short u16;

#define S_LEN 2048
#define EMB   1024
#define HID   1024
#define NB    4

using bf16x8 = __attribute__((ext_vector_type(8))) __bf16;
using f32x4  = __attribute__((ext_vector_type(4))) float;

// ---------- helpers ----------

__device__ __forceinline__ u16 f2bf(float f) {
  union { float f; uint32_t u; } c; c.f = f;
  uint32_t u = c.u;
  uint32_t r = (u + 0x7fffu + ((u >> 16) & 1u)) >> 16;  // RNE
  return (u16)r;
}

__device__ __forceinline__ void gld_lds16(const u16* g, u16* l) {
  auto gp = (const __attribute__((address_space(1))) uint32_t*)(uintptr_t)(const void*)g;
  auto lp = (__attribute__((address_space(3))) uint32_t*)(uintptr_t)(void*)l;
  __builtin_amdgcn_global_load_lds(gp, lp, 16, 0, 0);
}

// ---------- fp32 -> bf16 converts ----------

__global__ void cvt_f32_bf16(const float* __restrict__ in, u16* __restrict__ out, int n4) {
  int i = blockIdx.x * blockDim.x + threadIdx.x;
  int stride = gridDim.x * blockDim.x;
  for (; i < n4; i += stride) {
    float4 v = reinterpret_cast<const float4*>(in)[i];
    reinterpret_cast<ushort4*>(out)[i] =
      make_ushort4(f2bf(v.x), f2bf(v.y), f2bf(v.z), f2bf(v.w));
  }
}

__global__ void cvt3_f32_bf16(const float* __restrict__ a, const float* __restrict__ b,
                              const float* __restrict__ c, u16* __restrict__ out, int n4) {
  const float* src = (blockIdx.y == 0) ? a : (blockIdx.y == 1) ? b : c;
  u16* dst = out + (size_t)blockIdx.y * (size_t)n4 * 4;
  int i = blockIdx.x * blockDim.x + threadIdx.x;
  int stride = gridDim.x * blockDim.x;
  for (; i < n4; i += stride) {
    float4 v = reinterpret_cast<const float4*>(src)[i];
    reinterpret_cast<ushort4*>(dst)[i] =
      make_ushort4(f2bf(v.x), f2bf(v.y), f2bf(v.z), f2bf(v.w));
  }
}

// ============================================================================
// gemm_qkv8: m201-style 8-phase 256x256 GEMM for the fused QKV projection.
// A = xb [8192][1024], B = wqkv [3072][1024] (B^T layout), K=1024.
// BK=64 per K-tile; 2 K-tiles per iter (dbuf0, dbuf1); 8 phases per iter.
// Half-tiles split along K: each half = 256 rows x 32 cols = 16 KB.
// LDS map (u16 units): dbuf d*32768 + { Ak0:0, Ak1:8192, Bk0:16384, Bk1:24576 }
// Phase p: { ds_read own operands (4 or 8 b128); stage 1 half (2 gld_lds);
//            [vmcnt(4) at ph4/ph8]; s_barrier; (lgkm by compiler);
//            setprio(1); 16 MFMA; setprio(0); s_barrier }
// Stage slots (iter i, T=2i):  ph1:T+1.Ak1@d1  ph2:T+1.Bk1@d1  ph3:T+2.Ak0@d0
//   ph4:T+2.Bk0@d0+VM  ph5:T+2.Ak1@d0  ph6:T+2.Bk1@d0  ph7:T+3.Ak0@d1
//   ph8:T+3.Bk0@d1+VM      (ledger verified: writes hit dead regions only;
//   vmcnt(4) at ph4 covers all of T+1 before ph5; at ph8 covers T+2 before
//   next ph1; 2 half-tiles stay in flight -> vmcnt never drains)
// Swizzle st_16x32 (involution, 32B flip keyed on row-bit-3): applied to the
// global SOURCE address on stage (LDS dest linear) and to the ds_read chunk.
// ============================================================================

__global__ __launch_bounds__(512, 2)
void gemm_qkv8(const u16* __restrict__ A, const u16* __restrict__ Bw, u16* __restrict__ QK,
               const float* __restrict__ b0, const float* __restrict__ b1,
               const float* __restrict__ b2, u16* __restrict__ VT)
{
  constexpr int  K  = 1024;
  constexpr int  NTILE = K / 64;        // 16
  constexpr long M  = (long)NB * S_LEN; // 8192

  __shared__ __align__(16) u16 smem[65536];   // 128 KB

  const int tid = threadIdx.x;
  const int l   = tid & 63;
  const int w   = tid >> 6;
  const int wr  = w >> 2;              // 0..1
  const int wc  = w & 3;               // 0..3
  const int bm  = blockIdx.y * 256;
  const int bn  = blockIdx.x * 256;

  // ---- staging source (pre-swizzled): lane covers (srow, chunk) of a half ----
  const int chunk = (l & 3) ^ (((l >> 5) & 1) << 1);
  const int srow  = w * 16 + (l >> 2);
  const u16* gbA = A  + (long)(bm + srow) * K + chunk * 8;
  const u16* gbB = Bw + (long)(bn + srow) * K + chunk * 8;

#define STG(gb, dstu16)                                         \
  do {                                                          \
    gld_lds16((gb),            smem + (dstu16) + w * 512);      \
    gld_lds16((gb) + 128L * K, smem + (dstu16) + 4096 + w * 512); \
  } while (0)

  // ---- fragment ds_read offsets (u16 units), swizzled chunk ----
  const int lr  = l & 15;
  const int kg  = l >> 4;
  const int kgp = kg ^ (((lr >> 3) & 1) << 1);
  int aoff[8], boff[4];
#pragma unroll
  for (int m = 0; m < 8; ++m) aoff[m] = (wr * 128 + m * 16 + lr) * 32 + kgp * 8;
#pragma unroll
  for (int n = 0; n < 4; ++n) boff[n] = 16384 + (wc * 64 + n * 16 + lr) * 32 + kgp * 8;

  f32x4 acc[8][4] = {};
  bf16x8 bv[4];

  // ---- prologue: T0 all 4 halves -> d0; T1.Ak0, T1.Bk0 -> d1 ----
  STG(gbA + 0 * 64 + 0,  0);
  STG(gbB + 0 * 64 + 0,  16384);
  STG(gbA + 0 * 64 + 32, 8192);
  STG(gbB + 0 * 64 + 32, 16384 + 8192);
  STG(gbA + 1 * 64 + 0,  32768);
  STG(gbB + 1 * 64 + 0,  32768 + 16384);
  asm volatile("s_waitcnt vmcnt(4)" ::: "memory");   // T0 landed; T1 halves in flight
  __builtin_amdgcn_s_barrier();
  asm volatile("" ::: "memory");

#define PHASE(d, ksub, mh, STAGE_STMT, VMSTMT)                                     \
  do {                                                                             \
    const u16* hb = smem + (d) * 32768 + (ksub) * 8192;                            \
    bf16x8 av[4];                                                                  \
    _Pragma("unroll")                                                              \
    for (int j = 0; j < 4; ++j)                                                    \
      av[j] = *reinterpret_cast<const bf16x8*>(hb + aoff[(mh) * 4 + j]);           \
    if ((mh) == 0) {                                                               \
      _Pragma("unroll")                                                            \
      for (int n = 0; n < 4; ++n)                                                  \
        bv[n] = *reinterpret_cast<const bf16x8*>(hb + boff[n]);                    \
    }                                                                              \
    STAGE_STMT;                                                                    \
    VMSTMT;                                                                        \
    asm volatile("" ::: "memory");                                                 \
    __builtin_amdgcn_s_barrier();                                                  \
    asm volatile("" ::: "memory");                                                 \
    __builtin_amdgcn_s_setprio(1);                                                 \
    _Pragma("unroll")                                                              \
    for (int j = 0; j < 4; ++j)                                                    \
      _Pragma("unroll")                                                            \
      for (int n = 0; n < 4; ++n)                                                  \
        acc[(mh) * 4 + j][n] =                                                     \
          __builtin_amdgcn_mfma_f32_16x16x32_bf16(av[j], bv[n],                    \
                                                  acc[(mh) * 4 + j][n], 0, 0, 0);  \
    __builtin_amdgcn_s_setprio(0);                                                 \
    asm volatile("" ::: "memory");                                                 \
    __builtin_amdgcn_s_barrier();                                                  \
    asm volatile("" ::: "memory");                                                 \
  } while (0)

#define VM4 asm volatile("s_waitcnt vmcnt(4)" ::: "memory")

#pragma unroll 1
  for (int i = 0; i < NTILE / 2; ++i) {
    const long t1 = 2 * i + 1;
    const long t2 = (2 * i + 2 < NTILE) ? 2 * i + 2 : NTILE - 1;
    const long t3 = (2 * i + 3 < NTILE) ? 2 * i + 3 : NTILE - 1;
    PHASE(0, 0, 0, STG(gbA + t1 * 64 + 32, 32768 + 8192), );            // ph1
    PHASE(0, 0, 1, STG(gbB + t1 * 64 + 32, 32768 + 16384 + 8192), );    // ph2
    PHASE(0, 1, 0, STG(gbA + t2 * 64 + 0,  0), );                        // ph3
    PHASE(0, 1, 1, STG(gbB + t2 * 64 + 0,  16384), VM4);                 // ph4
    PHASE(1, 0, 0, STG(gbA + t2 * 64 + 32, 8192), );                     // ph5
    PHASE(1, 0, 1, STG(gbB + t2 * 64 + 32, 16384 + 8192), );             // ph6
    PHASE(1, 1, 0, STG(gbA + t3 * 64 + 0,  32768), );                    // ph7
    PHASE(1, 1, 1, STG(gbB + t3 * 64 + 0,  32768 + 16384), VM4);         // ph8
  }
#undef PHASE
#undef VM4
#undef STG

  // ---- epilogue: fused QKV routing (C map: col=lane&15, row=(lane>>4)*4+q) ----
  const int sel = bn >> 10;          // 0=Q, 1=K, 2=V (block-uniform)
  const float* bias = (sel == 0) ? b0 : (sel == 1) ? b1 : b2;
#pragma unroll
  for (int n = 0; n < 4; ++n) {
    const int col = bn + wc * 64 + n * 16 + lr;
    const int h   = col & (HID - 1);
    const float bbv = bias[h];
#pragma unroll
    for (int m = 0; m < 8; ++m) {
      const int row0 = bm + wr * 128 + m * 16 + kg * 4;
      if (sel < 2) {
        u16* dst = QK + (long)sel * M * HID + (long)row0 * HID + h;
#pragma unroll
        for (int q = 0; q < 4; ++q)
          dst[(long)q * HID] = f2bf(acc[m][n][q] + bbv);
      } else {
        const int b = row0 >> 11;
        const int s = row0 & (S_LEN - 1);
        ushort4 o = make_ushort4(f2bf(acc[m][n][0] + bbv), f2bf(acc[m][n][1] + bbv),
                                 f2bf(acc[m][n][2] + bbv), f2bf(acc[m][n][3] + bbv));
        *reinterpret_cast<ushort4*>(VT + ((long)b * HID + h) * S_LEN + s) = o;
      }
    }
  }
}

// ============================================================================
// gemm_bt: 128x128 m97-structure GEMM, C[M,N] = A[M,K]*B[N,K]^T  (R2-proven)
// EPI 2: f32 out, *scale, causal mask, triangular grid (scores)
// EPI 3: f32 out, kend = bm+128 (causal PV)
// ============================================================================

#define BM 128
#define BN 128
#define BK 32

template<int EPI>
__global__ __launch_bounds__(256)
void gemm_bt(const u16* __restrict__ A, const u16* __restrict__ B, void* __restrict__ Cv,
             int M, int N, int K, long sA, long sB, long sC, float scale)
{
  const int z = blockIdx.z;
  A += (long)z * sA;
  B += (long)z * sB;

  __shared__ __align__(16) u16 As[BM * BK];
  __shared__ __align__(16) u16 Bs[BN * BK];

  const int t    = threadIdx.x;
  const int lane = t & 63;
  const int wave = t >> 6;
  const int wr   = wave >> 1, wc = wave & 1;

  int bm, bn;
  if constexpr (EPI == 2) {
    const int x = blockIdx.x;
    int bi = (int)((sqrtf(8.0f * (float)x + 1.0f) - 1.0f) * 0.5f);
    while ((bi + 1) * (bi + 2) / 2 <= x) ++bi;
    while (bi * (bi + 1) / 2 > x) --bi;
    bm = bi * BM;
    bn = (x - bi * (bi + 1) / 2) * BN;
  } else {
    bm = (gridDim.y - 1 - blockIdx.y) * BM;   // long blocks first
    bn = blockIdx.x * BN;
  }

  int kend = K;
  if constexpr (EPI == 3) kend = bm + BM;

  f32x4 acc[4][4] = {};

  const int r  = t >> 2, c8 = (t & 3) * 8;
  const u16* gA = A + (long)(bm + r) * K + c8;
  const u16* gB = B + (long)(bn + r) * K + c8;
  u16* sA0 = As + wave * 512;
  u16* sB0 = Bs + wave * 512;

  const int lr = lane & 15;
  const int kg = lane >> 4;
  const int aoff = (wr * 64 + lr) * BK + kg * 8;
  const int boff = (wc * 64 + lr) * BK + kg * 8;

  for (int kt = 0; kt < kend; kt += BK) {
    gld_lds16(gA,                sA0);
    gld_lds16(gA + 64 * (long)K, sA0 + 2048);
    gld_lds16(gB,                sB0);
    gld_lds16(gB + 64 * (long)K, sB0 + 2048);
    gA += BK; gB += BK;
    __syncthreads();

    bf16x8 af[4], bf[4];
#pragma unroll
    for (int i = 0; i < 4; ++i)
      af[i] = *reinterpret_cast<const bf16x8*>(&As[aoff + i * 16 * BK]);
#pragma unroll
    for (int j = 0; j < 4; ++j)
      bf[j] = *reinterpret_cast<const bf16x8*>(&Bs[boff + j * 16 * BK]);
#pragma unroll
    for (int i = 0; i < 4; ++i)
#pragma unroll
      for (int j = 0; j < 4; ++j)
        acc[i][j] = __builtin_amdgcn_mfma_f32_16x16x32_bf16(af[i], bf[j], acc[i][j], 0, 0, 0);
    __syncthreads();
  }

  const int cl = lane & 15;
  const int rg = lane >> 4;

  if constexpr (EPI == 2) {
    float* C = (float*)Cv + (long)z * sC;
#pragma unroll
    for (int j = 0; j < 4; ++j) {
      const int col = bn + wc * 64 + j * 16 + cl;
#pragma unroll
      for (int i = 0; i < 4; ++i) {
        const int row0 = bm + wr * 64 + i * 16 + rg * 4;
#pragma unroll
        for (int q = 0; q < 4; ++q) {
          const int row = row0 + q;
          float v = acc[i][j][q] * scale;
          if (col > row) v = -1e30f;
          C[(long)row * N + col] = v;
        }
      }
    }
  } else {
    float* C = (float*)Cv + (long)z * sC;
#pragma unroll
    for (int j = 0; j < 4; ++j) {
      const int col = bn + wc * 64 + j * 16 + cl;
#pragma unroll
      for (int i = 0; i < 4; ++i) {
        const int row0 = bm + wr * 64 + i * 16 + rg * 4;
#pragma unroll
        for (int q = 0; q < 4; ++q)
          C[(long)(row0 + q) * N + col] = acc[i][j][q];
      }
    }
  }
}

// ---------- causal row softmax: fp32 scores -> bf16 P (kend 128-aligned) ----------

__global__ __launch_bounds__(256)
void softmax_causal(const float* __restrict__ Sc, u16* __restrict__ P, long sS, long sP)
{
  const int row  = blockIdx.x;
  const int z    = blockIdx.y;
  const int kend = ((row >> 7) + 1) << 7;
  const float* srow = Sc + (long)z * sS + (long)row * S_LEN;
  u16*        prow = P  + (long)z * sP + (long)row * S_LEN;
  const int t = threadIdx.x;
  const int lane = t & 63, wave = t >> 6;

  const bool p0 = (4 * t) < kend;
  const bool p1 = (1024 + 4 * t) < kend;

  float4 v0 = make_float4(-1e30f, -1e30f, -1e30f, -1e30f);
  float4 v1 = v0;
  if (p0) v0 = reinterpret_cast<const float4*>(srow)[t];
  if (p1) v1 = reinterpret_cast<const float4*>(srow)[t + 256];

  float mx = fmaxf(fmaxf(fmaxf(v0.x, v0.y), fmaxf(v0.z, v0.w)),
                   fmaxf(fmaxf(v1.x, v1.y), fmaxf(v1.z, v1.w)));

  __shared__ float red[8];
#pragma unroll
  for (int off = 32; off; off >>= 1) mx = fmaxf(mx, __shfl_down(mx, off));
  if (lane == 0) red[wave] = mx;
  __syncthreads();
  mx = fmaxf(fmaxf(red[0], red[1]), fmaxf(red[2], red[3]));

  float e[8];
  e[0] = __expf(v0.x - mx); e[1] = __expf(v0.y - mx);
  e[2] = __expf(v0.z - mx); e[3] = __expf(v0.w - mx);
  e[4] = __expf(v1.x - mx); e[5] = __expf(v1.y - mx);
  e[6] = __expf(v1.z - mx); e[7] = __expf(v1.w - mx);

  float sm = ((e[0] + e[1]) + (e[2] + e[3])) + ((e[4] + e[5]) + (e[6] + e[7]));
#pragma unroll
  for (int off = 32; off; off >>= 1) sm += __shfl_down(sm, off);
  if (lane == 0) red[4 + wave] = sm;
  __syncthreads();
  sm = (red[4] + red[5]) + (red[6] + red[7]);

  const float inv = 1.0f / sm;
  if (p0)
    reinterpret_cast<ushort4*>(prow)[t] =
      make_ushort4(f2bf(e[0]*inv), f2bf(e[1]*inv), f2bf(e[2]*inv), f2bf(e[3]*inv));
  if (p1)
    reinterpret_cast<ushort4*>(prow)[t + 256] =
      make_ushort4(f2bf(e[4]*inv), f2bf(e[5]*inv), f2bf(e[6]*inv), f2bf(e[7]*inv));
}

// ---------- launch ----------

extern "C" void kernel_launch(void* const* d_in, const int* in_sizes, int n_in,
                              void* d_out, int out_size, void* d_ws, size_t ws_size,
                              hipStream_t stream)
{
  const float* x  = (const float*)d_in[0];
  const float* Wq = (const float*)d_in[1];
  const float* bq = (const float*)d_in[2];
  const float* Wk = (const float*)d_in[3];
  const float* bk = (const float*)d_in[4];
  const float* Wv = (const float*)d_in[5];
  const float* bv = (const float*)d_in[6];
  float* out = (float*)d_out;

  const long M = (long)NB * S_LEN;  // 8192

  u16* xb  = (u16*)d_ws;
  u16* wqb = xb  + M * EMB;         // wq/wk/wv contiguous -> fused [3072,1024]
  u16* Qb  = wqb + 3L * HID * EMB;  // Q then K contiguous
  u16* Kb  = Qb  + M * HID;
  u16* VT  = Kb  + M * HID;
  char* rest = (char*)(VT + M * HID);
  const size_t used  = (size_t)(rest - (char*)d_ws);
  const size_t ssz   = (size_t)S_LEN * S_LEN;
  const size_t need4 = used + (size_t)NB * ssz * 4 + (size_t)NB * ssz * 2;
  const int nb = (ws_size >= need4) ? NB : 1;
  float* scores = (float*)rest;
  u16*   P      = (u16*)(rest + (size_t)nb * ssz * 4);

  // fp32 -> bf16
  cvt_f32_bf16<<<2048, 256, 0, stream>>>(x, xb, (int)(M * EMB / 4));
  cvt3_f32_bf16<<<dim3(512, 3), 256, 0, stream>>>(Wq, Wk, Wv, wqb, HID * EMB / 4);

  // fused QKV projection: 8-phase 256^2 template
  gemm_qkv8<<<dim3(3 * HID / 256, M / 256), 512, 0, stream>>>(xb, wqb, Qb, bq, bk, bv, VT);

  const float scale = 0.03125f;  // 1/sqrt(1024)
  const int NTb = S_LEN / BM;              // 16 block-rows
  const int TRI = NTb * (NTb + 1) / 2;     // 136 lower-tri blocks

  if (nb == NB) {
    dim3 gs(TRI, 1, NB);
    gemm_bt<2><<<gs, 256, 0, stream>>>(Qb, Kb, scores, S_LEN, S_LEN, HID,
                                       (long)S_LEN * HID, (long)S_LEN * HID, (long)ssz, scale);
    softmax_causal<<<dim3(S_LEN, NB), 256, 0, stream>>>(scores, P, (long)ssz, (long)ssz);
    dim3 gv(HID / BN, S_LEN / BM, NB);
    gemm_bt<3><<<gv, 256, 0, stream>>>(P, VT, out, S_LEN, HID, S_LEN,
                                       (long)ssz, (long)HID * S_LEN, (long)S_LEN * HID, 1.0f);
  } else {
    for (int b = 0; b < NB; ++b) {
      const u16* Qbb = Qb + (long)b * S_LEN * HID;
      const u16* Kbb = Kb + (long)b * S_LEN * HID;
      const u16* VTb = VT + (long)b * HID * S_LEN;
      float* outb = out + (long)b * S_LEN * HID;
      dim3 gs(TRI, 1, 1);
      gemm_bt<2><<<gs, 256, 0, stream>>>(Qbb, Kbb, scores, S_LEN, S_LEN, HID, 0, 0, 0, scale);
      softmax_causal<<<dim3(S_LEN, 1), 256, 0, stream>>>(scores, P, 0, 0);
      dim3 gv(HID / BN, S_LEN / BM, 1);
      gemm_bt<3><<<gv, 256, 0, stream>>>(P, VTb, outb, S_LEN, HID, S_LEN, 0, 0, 0, 1.0f);
    }
  }
}

// Round 6
// 190.089 us; speedup vs baseline: 1.1264x; 1.1056x over previous
//
#include <hip/hip_runtime.h>
#include <cstdint>
#include <cstddef>
#include <math.h>

typedef unsigned short u16;

#define S_LEN 2048
#define EMB   1024
#define HID   1024
#define NB    4

using bf16x8 = __attribute__((ext_vector_type(8))) __bf16;
using f32x4  = __attribute__((ext_vector_type(4))) float;

// ---------- helpers ----------

__device__ __forceinline__ u16 f2bf(float f) {
  union { float f; uint32_t u; } c; c.f = f;
  uint32_t u = c.u;
  uint32_t r = (u + 0x7fffu + ((u >> 16) & 1u)) >> 16;  // RNE
  return (u16)r;
}

__device__ __forceinline__ void gld_lds16(const u16* g, u16* l) {
  auto gp = (const __attribute__((address_space(1))) uint32_t*)(uintptr_t)(const void*)g;
  auto lp = (__attribute__((address_space(3))) uint32_t*)(uintptr_t)(void*)l;
  __builtin_amdgcn_global_load_lds(gp, lp, 16, 0, 0);
}

// ---------- fp32 -> bf16 converts ----------

__global__ void cvt_f32_bf16(const float* __restrict__ in, u16* __restrict__ out, int n4) {
  int i = blockIdx.x * blockDim.x + threadIdx.x;
  int stride = gridDim.x * blockDim.x;
  for (; i < n4; i += stride) {
    float4 v = reinterpret_cast<const float4*>(in)[i];
    reinterpret_cast<ushort4*>(out)[i] =
      make_ushort4(f2bf(v.x), f2bf(v.y), f2bf(v.z), f2bf(v.w));
  }
}

__global__ void cvt3_f32_bf16(const float* __restrict__ a, const float* __restrict__ b,
                              const float* __restrict__ c, u16* __restrict__ out, int n4) {
  const float* src = (blockIdx.y == 0) ? a : (blockIdx.y == 1) ? b : c;
  u16* dst = out + (size_t)blockIdx.y * (size_t)n4 * 4;
  int i = blockIdx.x * blockDim.x + threadIdx.x;
  int stride = gridDim.x * blockDim.x;
  for (; i < n4; i += stride) {
    float4 v = reinterpret_cast<const float4*>(src)[i];
    reinterpret_cast<ushort4*>(dst)[i] =
      make_ushort4(f2bf(v.x), f2bf(v.y), f2bf(v.z), f2bf(v.w));
  }
}

// ============================================================================
// gemm4p: 128x256 tile, BK=64, 8 waves (2Mx4N, 64x64 each), uniform pipeline.
// C[M,N] = A[M,K] * B[N,K]^T.
// LDS: 2 bufs x 48KB { A.k0:4096u16, A.k1:4096, B.k0:8192, B.k1:8192 }.
// Iter i = tiles (2i)->buf0, (2i+1)->buf1; 4 phases = (buf,ksub):
//   P1(0,0) P2(0,1) P3(1,0) P4(1,1).
// Each phase: { 8 ds_read own frags; stage ONE half-tile (A 1 + B 2 gld_lds)
//   for the phase 2 ahead; vmcnt(3); barrier; 16 MFMA; barrier }.
// Stage targets: P1->(2i+1).k0@buf1  P2->(2i+1).k1@buf1
//                P3->(2i+2).k0@buf0  P4->(2i+2).k1@buf0   (clamped at end)
// vmcnt(3) at each phase end waits exactly the half staged 2 phases earlier
// (needed next phase); 6 loads stay in flight, never drains in-loop.
// Ledger: every stage target's last reader finished >=2 barriers earlier.
// Chunk swizzle (involution, zero-conflict verified R5): physical chunk c
// holds logical chunk c ^ ((row>>3&1)<<1); applied at global source + ds_read.
// EPI 3: f32 out, kend=bm+128 (causal PV).  EPI 4: fused QKV routing.
// ============================================================================

template<int EPI>
__global__ __launch_bounds__(512, 2)
void gemm4p(const u16* __restrict__ A, const u16* __restrict__ Bw, void* __restrict__ Cv,
            const float* __restrict__ b0, const float* __restrict__ b1,
            const float* __restrict__ b2, u16* __restrict__ VT,
            int N, int K, long sA, long sB, long sC, float scale)
{
  const int z = blockIdx.z;
  A  += (long)z * sA;
  Bw += (long)z * sB;

  __shared__ __align__(16) u16 smem[49152];   // 96 KB

  const int tid = threadIdx.x;
  const int l   = tid & 63;
  const int w   = tid >> 6;
  const int wr  = w >> 2;              // 0..1
  const int wc  = w & 3;               // 0..3
  const int bm  = blockIdx.y * 128;
  const int bn  = blockIdx.x * 256;

  int kend = K;
  if constexpr (EPI == 3) kend = bm + 128;
  const int NTILE = kend >> 6;         // even

  // ---- staging lane geometry (pre-swizzled source chunk) ----
  const int arow = w * 16 + (l >> 2);                 // 0..127
  const int acs  = (l & 3) ^ (((l >> 5) & 1) << 1);   // chunk ^ row-bit3 flip
  const u16* gbA  = A  + (long)(bm + arow) * K + acs * 8;
  const u16* gbB  = Bw + (long)(bn + arow) * K + acs * 8;
  const u16* gbB2 = gbB + 128L * K;

#define STGH(t, s, dbase)                                                       \
  do {                                                                          \
    const long _o = (long)(t) * 64 + (s) * 32;                                  \
    gld_lds16(gbA  + _o, smem + (dbase) + (s) * 4096 + w * 512);                \
    gld_lds16(gbB  + _o, smem + (dbase) + 8192 + (s) * 8192 + w * 512);         \
    gld_lds16(gbB2 + _o, smem + (dbase) + 8192 + (s) * 8192 + 4096 + w * 512);  \
  } while (0)

  // ---- fragment ds_read offsets (region-local, u16 units), swizzled ----
  const int lr  = l & 15;
  const int kg  = l >> 4;
  const int kgp = kg ^ (((lr >> 3) & 1) << 1);
  int aoff[4], boff[4];
#pragma unroll
  for (int m = 0; m < 4; ++m) aoff[m] = (wr * 64 + m * 16 + lr) * 32 + kgp * 8;
#pragma unroll
  for (int n = 0; n < 4; ++n) boff[n] = (wc * 64 + n * 16 + lr) * 32 + kgp * 8;

  f32x4 acc[4][4] = {};

  // ---- prologue: tile 0 (both halves) -> buf0; drain once ----
  STGH(0, 0, 0);
  STGH(0, 1, 0);
  asm volatile("s_waitcnt vmcnt(0)" ::: "memory");
  __builtin_amdgcn_s_barrier();
  asm volatile("" ::: "memory");

#define PHASE(d, s, STGSTMT)                                                    \
  do {                                                                          \
    const u16* hA = smem + (d) * 24576 + (s) * 4096;                            \
    const u16* hB = smem + (d) * 24576 + 8192 + (s) * 8192;                     \
    bf16x8 av[4], bv[4];                                                        \
    _Pragma("unroll")                                                           \
    for (int m_ = 0; m_ < 4; ++m_)                                              \
      av[m_] = *reinterpret_cast<const bf16x8*>(hA + aoff[m_]);                 \
    _Pragma("unroll")                                                           \
    for (int n_ = 0; n_ < 4; ++n_)                                              \
      bv[n_] = *reinterpret_cast<const bf16x8*>(hB + boff[n_]);                 \
    STGSTMT;                                                                    \
    asm volatile("s_waitcnt vmcnt(3)" ::: "memory");                            \
    __builtin_amdgcn_s_barrier();                                               \
    asm volatile("" ::: "memory");                                              \
    __builtin_amdgcn_s_setprio(1);                                              \
    _Pragma("unroll")                                                           \
    for (int m_ = 0; m_ < 4; ++m_)                                              \
      _Pragma("unroll")                                                         \
      for (int n_ = 0; n_ < 4; ++n_)                                            \
        acc[m_][n_] = __builtin_amdgcn_mfma_f32_16x16x32_bf16(                  \
            av[m_], bv[n_], acc[m_][n_], 0, 0, 0);                              \
    __builtin_amdgcn_s_setprio(0);                                              \
    asm volatile("" ::: "memory");                                              \
    __builtin_amdgcn_s_barrier();                                               \
    asm volatile("" ::: "memory");                                              \
  } while (0)

#pragma unroll 1
  for (int i = 0; i < NTILE / 2; ++i) {
    const int t1 = 2 * i + 1;
    const int t2 = (2 * i + 2 < NTILE) ? 2 * i + 2 : NTILE - 1;
    PHASE(0, 0, STGH(t1, 0, 24576));
    PHASE(0, 1, STGH(t1, 1, 24576));
    PHASE(1, 0, STGH(t2, 0, 0));
    PHASE(1, 1, STGH(t2, 1, 0));
  }
#undef PHASE
#undef STGH

  // ---- epilogue: C map col=lane&15, row=(lane>>4)*4+q ----
  if constexpr (EPI == 3) {            // f32 plain (causal PV -> output)
    float* C = (float*)Cv + (long)z * sC;
#pragma unroll
    for (int n = 0; n < 4; ++n) {
      const int col = bn + wc * 64 + n * 16 + lr;
#pragma unroll
      for (int m = 0; m < 4; ++m) {
        const int row0 = bm + wr * 64 + m * 16 + kg * 4;
#pragma unroll
        for (int q = 0; q < 4; ++q)
          C[(long)(row0 + q) * N + col] = acc[m][n][q];
      }
    }
  } else {                             // EPI 4: fused QKV routing
    constexpr long M = (long)NB * S_LEN;
    const int sel = bn >> 10;          // 0=Q, 1=K, 2=V (block-uniform, BN=256 | 1024)
    const float* bias = (sel == 0) ? b0 : (sel == 1) ? b1 : b2;
    u16* QK = (u16*)Cv;
#pragma unroll
    for (int n = 0; n < 4; ++n) {
      const int col = bn + wc * 64 + n * 16 + lr;
      const int h   = col & (HID - 1);
      const float bbv = bias[h];
#pragma unroll
      for (int m = 0; m < 4; ++m) {
        const int row0 = bm + wr * 64 + m * 16 + kg * 4;
        if (sel < 2) {
          u16* dst = QK + (long)sel * M * HID + (long)row0 * HID + h;
#pragma unroll
          for (int q = 0; q < 4; ++q)
            dst[(long)q * HID] = f2bf(acc[m][n][q] + bbv);
        } else {
          const int b = row0 >> 11;
          const int s = row0 & (S_LEN - 1);
          ushort4 o = make_ushort4(f2bf(acc[m][n][0] + bbv), f2bf(acc[m][n][1] + bbv),
                                   f2bf(acc[m][n][2] + bbv), f2bf(acc[m][n][3] + bbv));
          *reinterpret_cast<ushort4*>(VT + ((long)b * HID + h) * S_LEN + s) = o;
        }
      }
    }
  }
}

// ============================================================================
// gemm_bt: 128x128 m97-structure GEMM (scores only)
// EPI 2: f32 out, *scale, causal mask, triangular grid
// ============================================================================

#define BM 128
#define BN 128
#define BK 32

__global__ __launch_bounds__(256)
void gemm_bt2(const u16* __restrict__ A, const u16* __restrict__ B, float* __restrict__ Cv,
              int N, int K, long sA, long sB, long sC, float scale)
{
  const int z = blockIdx.z;
  A += (long)z * sA;
  B += (long)z * sB;

  __shared__ __align__(16) u16 As[BM * BK];
  __shared__ __align__(16) u16 Bs[BN * BK];

  const int t    = threadIdx.x;
  const int lane = t & 63;
  const int wave = t >> 6;
  const int wr   = wave >> 1, wc = wave & 1;

  const int x = blockIdx.x;
  int bi = (int)((sqrtf(8.0f * (float)x + 1.0f) - 1.0f) * 0.5f);
  while ((bi + 1) * (bi + 2) / 2 <= x) ++bi;
  while (bi * (bi + 1) / 2 > x) --bi;
  const int bm = bi * BM;
  const int bn = (x - bi * (bi + 1) / 2) * BN;

  f32x4 acc[4][4] = {};

  const int r  = t >> 2, c8 = (t & 3) * 8;
  const u16* gA = A + (long)(bm + r) * K + c8;
  const u16* gB = B + (long)(bn + r) * K + c8;
  u16* sA0 = As + wave * 512;
  u16* sB0 = Bs + wave * 512;

  const int lr = lane & 15;
  const int kg = lane >> 4;
  const int aoff = (wr * 64 + lr) * BK + kg * 8;
  const int boff = (wc * 64 + lr) * BK + kg * 8;

  for (int kt = 0; kt < K; kt += BK) {
    gld_lds16(gA,                sA0);
    gld_lds16(gA + 64 * (long)K, sA0 + 2048);
    gld_lds16(gB,                sB0);
    gld_lds16(gB + 64 * (long)K, sB0 + 2048);
    gA += BK; gB += BK;
    __syncthreads();

    bf16x8 af[4], bf[4];
#pragma unroll
    for (int i = 0; i < 4; ++i)
      af[i] = *reinterpret_cast<const bf16x8*>(&As[aoff + i * 16 * BK]);
#pragma unroll
    for (int j = 0; j < 4; ++j)
      bf[j] = *reinterpret_cast<const bf16x8*>(&Bs[boff + j * 16 * BK]);
#pragma unroll
    for (int i = 0; i < 4; ++i)
#pragma unroll
      for (int j = 0; j < 4; ++j)
        acc[i][j] = __builtin_amdgcn_mfma_f32_16x16x32_bf16(af[i], bf[j], acc[i][j], 0, 0, 0);
    __syncthreads();
  }

  float* C = Cv + (long)z * sC;
#pragma unroll
  for (int j = 0; j < 4; ++j) {
    const int col = bn + wc * 64 + j * 16 + lr;
#pragma unroll
    for (int i = 0; i < 4; ++i) {
      const int row0 = bm + wr * 64 + i * 16 + kg * 4;
#pragma unroll
      for (int q = 0; q < 4; ++q) {
        const int row = row0 + q;
        float v = acc[i][j][q] * scale;
        if (col > row) v = -1e30f;
        C[(long)row * N + col] = v;
      }
    }
  }
}

// ---------- causal row softmax: fp32 scores -> bf16 P (kend 128-aligned) ----------

__global__ __launch_bounds__(256)
void softmax_causal(const float* __restrict__ Sc, u16* __restrict__ P, long sS, long sP)
{
  const int row  = blockIdx.x;
  const int z    = blockIdx.y;
  const int kend = ((row >> 7) + 1) << 7;
  const float* srow = Sc + (long)z * sS + (long)row * S_LEN;
  u16*        prow = P  + (long)z * sP + (long)row * S_LEN;
  const int t = threadIdx.x;
  const int lane = t & 63, wave = t >> 6;

  const bool p0 = (4 * t) < kend;
  const bool p1 = (1024 + 4 * t) < kend;

  float4 v0 = make_float4(-1e30f, -1e30f, -1e30f, -1e30f);
  float4 v1 = v0;
  if (p0) v0 = reinterpret_cast<const float4*>(srow)[t];
  if (p1) v1 = reinterpret_cast<const float4*>(srow)[t + 256];

  float mx = fmaxf(fmaxf(fmaxf(v0.x, v0.y), fmaxf(v0.z, v0.w)),
                   fmaxf(fmaxf(v1.x, v1.y), fmaxf(v1.z, v1.w)));

  __shared__ float red[8];
#pragma unroll
  for (int off = 32; off; off >>= 1) mx = fmaxf(mx, __shfl_down(mx, off));
  if (lane == 0) red[wave] = mx;
  __syncthreads();
  mx = fmaxf(fmaxf(red[0], red[1]), fmaxf(red[2], red[3]));

  float e[8];
  e[0] = __expf(v0.x - mx); e[1] = __expf(v0.y - mx);
  e[2] = __expf(v0.z - mx); e[3] = __expf(v0.w - mx);
  e[4] = __expf(v1.x - mx); e[5] = __expf(v1.y - mx);
  e[6] = __expf(v1.z - mx); e[7] = __expf(v1.w - mx);

  float sm = ((e[0] + e[1]) + (e[2] + e[3])) + ((e[4] + e[5]) + (e[6] + e[7]));
#pragma unroll
  for (int off = 32; off; off >>= 1) sm += __shfl_down(sm, off);
  if (lane == 0) red[4 + wave] = sm;
  __syncthreads();
  sm = (red[4] + red[5]) + (red[6] + red[7]);

  const float inv = 1.0f / sm;
  if (p0)
    reinterpret_cast<ushort4*>(prow)[t] =
      make_ushort4(f2bf(e[0]*inv), f2bf(e[1]*inv), f2bf(e[2]*inv), f2bf(e[3]*inv));
  if (p1)
    reinterpret_cast<ushort4*>(prow)[t + 256] =
      make_ushort4(f2bf(e[4]*inv), f2bf(e[5]*inv), f2bf(e[6]*inv), f2bf(e[7]*inv));
}

// ---------- launch ----------

extern "C" void kernel_launch(void* const* d_in, const int* in_sizes, int n_in,
                              void* d_out, int out_size, void* d_ws, size_t ws_size,
                              hipStream_t stream)
{
  const float* x  = (const float*)d_in[0];
  const float* Wq = (const float*)d_in[1];
  const float* bq = (const float*)d_in[2];
  const float* Wk = (const float*)d_in[3];
  const float* bk = (const float*)d_in[4];
  const float* Wv = (const float*)d_in[5];
  const float* bv = (const float*)d_in[6];
  float* out = (float*)d_out;

  const long M = (long)NB * S_LEN;  // 8192

  u16* xb  = (u16*)d_ws;
  u16* wqb = xb  + M * EMB;         // wq/wk/wv contiguous -> fused [3072,1024]
  u16* Qb  = wqb + 3L * HID * EMB;  // Q then K contiguous
  u16* Kb  = Qb  + M * HID;
  u16* VT  = Kb  + M * HID;
  char* rest = (char*)(VT + M * HID);
  const size_t used  = (size_t)(rest - (char*)d_ws);
  const size_t ssz   = (size_t)S_LEN * S_LEN;
  const size_t need4 = used + (size_t)NB * ssz * 4 + (size_t)NB * ssz * 2;
  const int nb = (ws_size >= need4) ? NB : 1;
  float* scores = (float*)rest;
  u16*   P      = (u16*)(rest + (size_t)nb * ssz * 4);

  // fp32 -> bf16
  cvt_f32_bf16<<<2048, 256, 0, stream>>>(x, xb, (int)(M * EMB / 4));
  cvt3_f32_bf16<<<dim3(512, 3), 256, 0, stream>>>(Wq, Wk, Wv, wqb, HID * EMB / 4);

  // fused QKV projection: 128x256 pipeline, grid 768 = 3 exact rounds
  gemm4p<4><<<dim3(12, 64, 1), 512, 0, stream>>>(xb, wqb, Qb, bq, bk, bv, VT,
                                                 3 * HID, EMB, 0, 0, 0, 1.0f);

  const float scale = 0.03125f;  // 1/sqrt(1024)
  const int NTb = S_LEN / BM;              // 16 block-rows
  const int TRI = NTb * (NTb + 1) / 2;     // 136 lower-tri blocks

  if (nb == NB) {
    dim3 gs(TRI, 1, NB);
    gemm_bt2<<<gs, 256, 0, stream>>>(Qb, Kb, scores, S_LEN, HID,
                                     (long)S_LEN * HID, (long)S_LEN * HID, (long)ssz, scale);
    softmax_causal<<<dim3(S_LEN, NB), 256, 0, stream>>>(scores, P, (long)ssz, (long)ssz);
    // causal PV: grid 4x16x4 = 256 = 1 exact round, kend = bm+128
    gemm4p<3><<<dim3(HID / 256, S_LEN / 128, NB), 512, 0, stream>>>(
        P, VT, out, nullptr, nullptr, nullptr, nullptr,
        HID, S_LEN, (long)ssz, (long)HID * S_LEN, (long)S_LEN * HID, 1.0f);
  } else {
    for (int b = 0; b < NB; ++b) {
      const u16* Qbb = Qb + (long)b * S_LEN * HID;
      const u16* Kbb = Kb + (long)b * S_LEN * HID;
      const u16* VTb = VT + (long)b * HID * S_LEN;
      float* outb = out + (long)b * S_LEN * HID;
      dim3 gs(TRI, 1, 1);
      gemm_bt2<<<gs, 256, 0, stream>>>(Qbb, Kbb, scores, S_LEN, HID, 0, 0, 0, scale);
      softmax_causal<<<dim3(S_LEN, 1), 256, 0, stream>>>(scores, P, 0, 0);
      gemm4p<3><<<dim3(HID / 256, S_LEN / 128, 1), 512, 0, stream>>>(
          P, VTb, outb, nullptr, nullptr, nullptr, nullptr,
          HID, S_LEN, 0, 0, 0, 1.0f);
    }
  }
}